// Round 10
// baseline (10716.047 us; speedup 1.0000x reference)
//
#include <hip/hip_runtime.h>

// PositionCloser round 10: split-K lockstep wave pair.
// Evidence R1-R9: 128-word weight arrays always get split into AGPRs -> one
// cross-file move per use (~2x issue tax); 1 wave/SIMD has no TLP. Fix both:
// each wave holds HALF of W_hh (64 words -> fits arch VGPRs), both waves
// matvec in parallel (phase A), wave0 does gates/h-update while wave1 does a
// chunk-lagged loss step (phase B). 2 __syncthreads per step; h/partials
// ping-pong through small LDS buffers; loss h-ring is deterministic under
// lockstep (no flags/spins). 1024 blocks x 128 thr = 2048 waves = 2/SIMD.

#define CH  128
#define HID 64

typedef __fp16 f16x2 __attribute__((ext_vector_type(2)));

__device__ __forceinline__ float rlf(float v, int l) {
  return __builtin_bit_cast(float, __builtin_amdgcn_readlane(__builtin_bit_cast(int, v), l));
}
__device__ __forceinline__ int rli(int v, int l) { return __builtin_amdgcn_readlane(v, l); }
__device__ __forceinline__ int packh(float a, float b) {
  return __builtin_bit_cast(int, __builtin_amdgcn_cvt_pkrtz(a, b));
}
__device__ __forceinline__ f16x2 h2(int v) { return __builtin_bit_cast(f16x2, v); }
__device__ __forceinline__ float frcp(float x) { return __builtin_amdgcn_rcpf(x); }
__device__ __forceinline__ float sigm(float x) { return frcp(1.0f + __expf(-x)); }
__device__ __forceinline__ float tanh_(float x) {
  float e = __expf(2.0f * x);
  return 1.0f - 2.0f * frcp(e + 1.0f);
}
template <int CTRL, int RMASK>
__device__ __forceinline__ float dpp_add(float v) {
  int x = __builtin_amdgcn_update_dpp(0, __builtin_bit_cast(int, v), CTRL, RMASK, 0xF, true);
  return v + __builtin_bit_cast(float, x);
}
__device__ __forceinline__ float dpp_xor1(float v) {  // quad_perm [1,0,3,2]
  int x = __builtin_amdgcn_update_dpp(0, __builtin_bit_cast(int, v), 0xB1, 0xF, 0xF, true);
  return __builtin_bit_cast(float, x);
}
__device__ __forceinline__ float dpp_wave_sum(float v) {  // total lands in lane 63
  v = dpp_add<0x111, 0xF>(v);
  v = dpp_add<0x112, 0xF>(v);
  v = dpp_add<0x114, 0xF>(v);
  v = dpp_add<0x118, 0xF>(v);
  v = dpp_add<0x142, 0xA>(v);   // row_bcast:15
  v = dpp_add<0x143, 0xC>(v);   // row_bcast:31
  return v;
}

__global__ __launch_bounds__(128)
void pc_lstm_kernel(const int* __restrict__ inds,
                    const float* __restrict__ p,
                    const float* __restrict__ ls_probs,
                    const float* __restrict__ open_probs,
                    const int* __restrict__ open_slices,
                    const float* __restrict__ open_hx,
                    const float* __restrict__ W_ih,
                    const float* __restrict__ W_hh,
                    const float* __restrict__ b_ih,
                    const float* __restrict__ b_hh,
                    const float* __restrict__ W_out,
                    const float* __restrict__ b_out,
                    const int* __restrict__ n_chunks_p,
                    float* __restrict__ out)
{
  __shared__ __fp16 ring[2][CH][HID];   // 32 KB: h history for the lagged loss
  __shared__ int    hpbuf[16];          // packed-h words 16..31 (h[32..63]) for wave1
  __shared__ float  pbuf[64][4];        // wave1's 4 gate partials per lane

  const int tid  = threadIdx.x;
  const int wv   = tid >> 6;            // 0 = gates+K-half0, 1 = K-half1+loss
  const int lane = tid & 63;
  const int s    = blockIdx.x;          // one sequence per block
  const int n_chunks = n_chunks_p[0];
  const int tbase = inds[s >> 4] + (s & 15);
  const float2* p2 = (const float2*)p;

  // ---- weights: each wave holds its K-half (64 packed words -> arch VGPRs)
  int W0[16], W1[16], W2[16], W3[16];
  {
    const int kb = wv * 32;
    const float2* r0 = (const float2*)(W_hh + (0 * HID + lane) * HID + kb);
    const float2* r1 = (const float2*)(W_hh + (1 * HID + lane) * HID + kb);
    const float2* r2 = (const float2*)(W_hh + (2 * HID + lane) * HID + kb);
    const float2* r3 = (const float2*)(W_hh + (3 * HID + lane) * HID + kb);
#pragma unroll
    for (int j = 0; j < 16; ++j) {
      float2 v0 = r0[j], v1 = r1[j], v2 = r2[j], v3 = r3[j];
      W0[j] = packh(v0.x, v0.y);
      W1[j] = packh(v1.x, v1.y);
      W2[j] = packh(v2.x, v2.y);
      W3[j] = packh(v3.x, v3.y);
    }
  }

  // ---- wave0 state
  float wxa[4], wxb[4], bb[4];
  float h = 0.0f, c = 0.0f;
  int   hp = 0;
  float2 nxtA, nxtB, xA, xB;
  // ---- wave1 state
  float wo = 0.0f, bout = 0.0f, OL = 0.0f, coef = 0.0f;
  float S = 1.0f, D = 1.0f, lsum = 0.0f, psum = 0.0f;
  float2 lagA, lagB;
  float lagLA = 0.0f, lagLB = 0.0f;

  if (wv == 0) {
#pragma unroll
    for (int g = 0; g < 4; ++g) {
      const int r = g * HID + lane;
      wxa[g] = W_ih[2 * r];
      wxb[g] = W_ih[2 * r + 1];
      bb[g]  = b_ih[r] + b_hh[r];
    }
    h = open_hx[(s * 2 + 0) * HID + lane];
    c = open_hx[(s * 2 + 1) * HID + lane];
    hp = packh(h, dpp_xor1(h));           // even lane 2w holds word w
    if (lane >= 32 && !(lane & 1)) hpbuf[(lane - 32) >> 1] = hp;
    nxtA = p2[tbase + lane];
    nxtB = p2[tbase + HID + lane];
  } else {
    wo   = W_out[lane];
    bout = b_out[0];
    const int os = open_slices[s];
    OL   = __logf(p[2 * os]) + __logf(p[2 * os + 1]);
    coef = open_probs[s] * (2.0f * ls_probs[s] - 1.0f);
  }
  __syncthreads();

  for (int off = 0; off < n_chunks; ++off) {
    if (wv == 0) {
      const float2 curA = nxtA, curB = nxtB;
      const float px0 = rlf(curA.x, 0);
      const float px1 = rlf(curA.y, 0);
      xA.x = curA.x - px0; xA.y = curA.y - px1;
      xB.x = curB.x - px0; xB.y = curB.y - px1;
      if (off + 1 < n_chunks) {
        const int nb = tbase + (off + 1) * CH;
        nxtA = p2[nb + lane];
        nxtB = p2[nb + HID + lane];
      }
    } else {
      if (off) {                          // logs of the lagged chunk (off-1)
        lagLA = __logf(lagA.x) + __logf(lagA.y);
        lagLB = __logf(lagB.x) + __logf(lagB.y);
      }
      const int lb = tbase + off * CH;    // prefetch chunk off (lag for off+1)
      lagA = p2[lb + lane];
      lagB = p2[lb + HID + lane];
    }
    const int doloss = (off > 0);
    const int rpar = off & 1;

#pragma unroll
    for (int hf = 0; hf < 2; ++hf) {
#pragma unroll 1
      for (int tl = 0; tl < 64; ++tl) {
        const int tt = (hf << 6) + tl;
        float A0, A1, A2, A3;     // wave0 gate accumulators
        float hv = 0.0f;          // wave1 loss h

        // ================= phase A: both waves matvec their K-half =========
        if (wv == 0) {
          const float x0 = rlf(hf ? xB.x : xA.x, tl);
          const float x1 = rlf(hf ? xB.y : xA.y, tl);
          A0 = fmaf(x1, wxb[0], fmaf(x0, wxa[0], bb[0]));
          A1 = fmaf(x1, wxb[1], fmaf(x0, wxa[1], bb[1]));
          A2 = fmaf(x1, wxb[2], fmaf(x0, wxa[2], bb[2]));
          A3 = fmaf(x1, wxb[3], fmaf(x0, wxa[3], bb[3]));
#pragma unroll
          for (int j = 0; j < 16; ++j) {
            const f16x2 ha = h2(rli(hp, 2 * j));   // words 0..15 = h[0..31]
            A0 = __builtin_amdgcn_fdot2(ha, h2(W0[j]), A0, false);
            A1 = __builtin_amdgcn_fdot2(ha, h2(W1[j]), A1, false);
            A2 = __builtin_amdgcn_fdot2(ha, h2(W2[j]), A2, false);
            A3 = __builtin_amdgcn_fdot2(ha, h2(W3[j]), A3, false);
          }
        } else {
          const int hw = hpbuf[lane & 15];         // word 16+(lane&15)
          if (doloss) hv = (float)ring[rpar ^ 1][tt][lane];
          float P0 = 0.f, P1 = 0.f, P2 = 0.f, P3 = 0.f;
#pragma unroll
          for (int j = 0; j < 16; ++j) {
            const f16x2 hb = h2(rli(hw, j));       // word 16+j = h[32+2j..]
            P0 = __builtin_amdgcn_fdot2(hb, h2(W0[j]), P0, false);
            P1 = __builtin_amdgcn_fdot2(hb, h2(W1[j]), P1, false);
            P2 = __builtin_amdgcn_fdot2(hb, h2(W2[j]), P2, false);
            P3 = __builtin_amdgcn_fdot2(hb, h2(W3[j]), P3, false);
          }
          pbuf[lane][0] = P0; pbuf[lane][1] = P1;
          pbuf[lane][2] = P2; pbuf[lane][3] = P3;
          A0 = A1 = A2 = A3 = 0.0f;
        }
        __syncthreads();

        // ================= phase B: gates (w0) | lagged loss (w1) ==========
        if (wv == 0) {
          const float4 P = *(const float4*)&pbuf[lane][0];
          const float ig = sigm(A0 + P.x);
          const float fg = sigm(A1 + P.y);
          const float gg = tanh_(A2 + P.z);
          const float og = sigm(A3 + P.w);
          c = fmaf(fg, c, ig * gg);
          h = og * tanh_(c);
          hp = packh(h, dpp_xor1(h));
          if (lane >= 32 && !(lane & 1)) hpbuf[(lane - 32) >> 1] = hp;
          ring[rpar][tt][lane] = (__fp16)h;
        } else if (doloss) {
          const float z  = rlf(dpp_wave_sum(hv * wo), 63);
          const float pr = sigm(z + bout);
          const float Lt = hf ? rlf(lagLB, tl) : rlf(lagLA, tl);
          const float pn = (tt == 0) ? pr : pr * D;
          lsum = fmaf(pn, Lt, lsum);
          psum += pn;
          if (tt == 0)           D = S * (1.0f - pr);  // chunk t=0 undiscounted
          else if (tt < CH - 1)  D *= (1.0f - pr);
          else                   S = D;                // carry excludes (1-p_last)
        }
        __syncthreads();
      }
    }
  }

  // ---- drain: loss for the final chunk (wave1 only; wave0 exits) ----
  if (wv == 1) {
    lagLA = __logf(lagA.x) + __logf(lagA.y);
    lagLB = __logf(lagB.x) + __logf(lagB.y);
    const int rpar = (n_chunks - 1) & 1;
#pragma unroll 1
    for (int tt = 0; tt < CH; ++tt) {
      const float hv = (float)ring[rpar][tt][lane];
      const float z  = rlf(dpp_wave_sum(hv * wo), 63);
      const float pr = sigm(z + bout);
      const float Lt = (tt < 64) ? rlf(lagLA, tt) : rlf(lagLB, tt - 64);
      const float pn = (tt == 0) ? pr : pr * D;
      lsum = fmaf(pn, Lt, lsum);
      psum += pn;
      if (tt == 0)           D = S * (1.0f - pr);
      else if (tt < CH - 1)  D *= (1.0f - pr);
      else                   S = D;
    }
    if (lane == 0) atomicAdd(out, coef * (lsum - OL * psum));
  }
}

extern "C" void kernel_launch(void* const* d_in, const int* in_sizes, int n_in,
                              void* d_out, int out_size, void* d_ws, size_t ws_size,
                              hipStream_t stream) {
  (void)hipMemsetAsync(d_out, 0, sizeof(float), stream);

  pc_lstm_kernel<<<dim3(1024), dim3(128), 0, stream>>>(
      (const int*)d_in[0],    // inds
      (const float*)d_in[1],  // p
      (const float*)d_in[2],  // ls_probs
      (const float*)d_in[3],  // open_probs
      (const int*)d_in[4],    // open_slices
      (const float*)d_in[5],  // open_hx
      (const float*)d_in[6],  // W_ih
      (const float*)d_in[7],  // W_hh
      (const float*)d_in[8],  // b_ih
      (const float*)d_in[9],  // b_hh
      (const float*)d_in[10], // W_out
      (const float*)d_in[11], // b_out
      (const int*)d_in[12],   // n_chunks
      (float*)d_out);
}